// Round 1
// baseline (9805.732 us; speedup 1.0000x reference)
//
#include <hip/hip_runtime.h>
#include <hip/hip_bf16.h>
#include <math.h>

// Sizes (fixed by the problem)
#define Bz   512
#define Tz   128
#define INz  64
#define Hz   512
#define Gz   2048   // 4*H
#define TSz  32
#define PLz  32

#define MB 64
#define KB 64

// Workspace layout (floats): h_a | h_b | c | buf(B*TS*H) | Wc(G*H) | ctx(B*H) | part(4*B*H)
// total = 11,534,336 floats = 46.1 MB (ws must be at least this big)

// ---------------- init: zero h,c ; Wc = Wc_ih + Wc_hh ----------------
__global__ __launch_bounds__(256) void k_init(const float* __restrict__ Wc_ih,
                                              const float* __restrict__ Wc_hh,
                                              float* __restrict__ Wc,
                                              float* __restrict__ h0,
                                              float* __restrict__ cc) {
    int i = blockIdx.x * 256 + threadIdx.x;
    if (i < Gz * Hz) Wc[i] = Wc_ih[i] + Wc_hh[i];
    if (i < Bz * Hz) { h0[i] = 0.f; cc[i] = 0.f; }
}

// ---------------- fused LSTM step: gates GEMM + cell update ----------------
// gates[b,g] = bias[g] + (has_x ? x[b,t,:]@Wx[g,:] : 0) + h_in[b,:]@Wh[g,:]
// C-tile 64 batches x 64 gate-cols; col c -> gate g = (c>>4)*H + j0 + (c&15)
__global__ __launch_bounds__(256) void k_step(const float* __restrict__ x, int t,
                                              const float* __restrict__ Wx,
                                              const float* __restrict__ Wh,
                                              const float* __restrict__ bias,
                                              const float* __restrict__ h_in,
                                              float* __restrict__ h_out,
                                              float* __restrict__ c,
                                              float* __restrict__ buf, int slot) {
    __shared__ float At[KB][MB];   // [k][batch]
    __shared__ float Wt[KB][MB];   // [k][col]
    const int tid = threadIdx.x;
    const int tx = tid & 15, ty = tid >> 4;
    const int b0 = blockIdx.x * MB;   // 8 batch-blocks
    const int j0 = blockIdx.y * 16;   // 32 j-blocks
    const bool has_x = (x != nullptr);
    const int nk = has_x ? 9 : 8;     // K = 64(x) + 512(h)  or  512

    float acc[4][4] = {};

    for (int kc = 0; kc < nk; ++kc) {
        const bool is_x = has_x && (kc == 0);
        const int kbase = has_x ? (kc - 1) * KB : kc * KB;   // h-part k offset
        // ---- load tiles, transposed to [k][m] (coalesced 256B global reads) ----
        #pragma unroll
        for (int p = 0; p < 4; ++p) {
            const int row = p * 16 + ty;     // batch row / col index
            const int kk  = tx * 4;
            const float* asrc = is_x ? (x + ((size_t)(b0 + row) * Tz + t) * INz + kk)
                                     : (h_in + (size_t)(b0 + row) * Hz + kbase + kk);
            const float4 av = *(const float4*)asrc;
            At[kk + 0][row] = av.x; At[kk + 1][row] = av.y;
            At[kk + 2][row] = av.z; At[kk + 3][row] = av.w;
            const int cl = p * 16 + ty;                 // col: q=p, jj=ty
            const int g  = p * Hz + j0 + ty;
            const float* wsrc = is_x ? (Wx + (size_t)g * INz + kk)
                                     : (Wh + (size_t)g * Hz + kbase + kk);
            const float4 wv = *(const float4*)wsrc;
            Wt[kk + 0][cl] = wv.x; Wt[kk + 1][cl] = wv.y;
            Wt[kk + 2][cl] = wv.z; Wt[kk + 3][cl] = wv.w;
        }
        __syncthreads();
        // ---- 4x4 micro-tile, conflict-free ds_read_b128 ----
        #pragma unroll 16
        for (int kk = 0; kk < KB; ++kk) {
            const float4 a4 = *(const float4*)&At[kk][ty * 4];
            const float4 w4 = *(const float4*)&Wt[kk][tx * 4];
            const float ar[4] = {a4.x, a4.y, a4.z, a4.w};
            const float wr[4] = {w4.x, w4.y, w4.z, w4.w};
            #pragma unroll
            for (int i = 0; i < 4; ++i)
                #pragma unroll
                for (int j = 0; j < 4; ++j)
                    acc[i][j] = fmaf(ar[i], wr[j], acc[i][j]);
        }
        __syncthreads();
    }

    // ---- gates (+bias) -> LDS, reuse At as Gt[64][64] ----
    float* Gt = &At[0][0];
    {
        const int q = tx >> 2;
        const int jb = (tx & 3) * 4;
        const float4 bv = *(const float4*)(bias + q * Hz + j0 + jb);
        const float br[4] = {bv.x, bv.y, bv.z, bv.w};
        #pragma unroll
        for (int i = 0; i < 4; ++i) {
            float4 o;
            o.x = acc[i][0] + br[0]; o.y = acc[i][1] + br[1];
            o.z = acc[i][2] + br[2]; o.w = acc[i][3] + br[3];
            *(float4*)&Gt[(ty * 4 + i) * 64 + tx * 4] = o;
        }
    }
    __syncthreads();

    // ---- cell update: 64 batches x 16 j per block ----
    #pragma unroll
    for (int r = 0; r < 4; ++r) {
        const int idx = r * 256 + tid;
        const int bl = idx >> 4, jj = idx & 15;
        const int b = b0 + bl, j = j0 + jj;
        const float gi = Gt[bl * 64 +      jj];
        const float gf = Gt[bl * 64 + 16 + jj];
        const float gg = Gt[bl * 64 + 32 + jj];
        const float go = Gt[bl * 64 + 48 + jj];
        const float si = 1.f / (1.f + __expf(-gi));
        const float sf = 1.f / (1.f + __expf(-gf));
        const float so = 1.f / (1.f + __expf(-go));
        const size_t o = (size_t)b * Hz + j;
        const float cn = sf * c[o] + si * tanhf(gg);
        const float hn = so * tanhf(cn);
        c[o] = cn;
        h_out[o] = hn;
        if (slot >= 0) buf[((size_t)b * TSz + slot) * Hz + j] = hn;   // ring slot t&31
    }
}

// ---------------- decoder attention over ring buffer + append ----------------
__global__ __launch_bounds__(256) void k_attn(const float* __restrict__ h_t,
                                              float* __restrict__ buf,
                                              float* __restrict__ ctx,
                                              int base) {
    const int b = blockIdx.x;
    const int tid = threadIdx.x;
    __shared__ float sh[Hz];
    __shared__ float sa[TSz];
    for (int i = tid; i < Hz; i += 256) sh[i] = h_t[(size_t)b * Hz + i];
    __syncthreads();
    {   // scores: 32 dots of length 512; 8 lanes per score
        const int s = tid >> 3, l8 = tid & 7;
        const float* br = buf + ((size_t)b * TSz + ((base + s) & 31)) * Hz;
        float p = 0.f;
        for (int j = l8; j < Hz; j += 8) p = fmaf(sh[j], br[j], p);
        p += __shfl_xor(p, 1); p += __shfl_xor(p, 2); p += __shfl_xor(p, 4);
        if (l8 == 0) sa[s] = p;
    }
    __syncthreads();
    if (tid < TSz) {   // softmax over 32 (lanes 0..31 of wave 0)
        const float v = sa[tid];
        float m = v;
        #pragma unroll
        for (int d = 1; d < 32; d <<= 1) m = fmaxf(m, __shfl_xor(m, d));
        const float e = __expf(v - m);
        float ssum = e;
        #pragma unroll
        for (int d = 1; d < 32; d <<= 1) ssum += __shfl_xor(ssum, d);
        sa[tid] = e / ssum;
    }
    __syncthreads();
    for (int j = tid; j < Hz; j += 256) {   // ctx = a @ buf
        float a = 0.f;
        #pragma unroll
        for (int s2 = 0; s2 < TSz; ++s2)
            a = fmaf(sa[s2], buf[((size_t)b * TSz + ((base + s2) & 31)) * Hz + j], a);
        ctx[(size_t)b * Hz + j] = a;
    }
    __syncthreads();   // all reads of slot `base` done before overwrite
    for (int i = tid; i < Hz; i += 256) buf[((size_t)b * TSz + base) * Hz + i] = sh[i];
}

// ---------------- MLP partial GEMM: part[z] = concat(ctx,h)@W1.T over k-slice z ----------------
__global__ __launch_bounds__(256) void k_mlp(const float* __restrict__ ctx,
                                             const float* __restrict__ h_t,
                                             const float* __restrict__ W1,
                                             float* __restrict__ part) {
    __shared__ float At[KB][MB];
    __shared__ float Wt[KB][MB];
    const int tid = threadIdx.x;
    const int tx = tid & 15, ty = tid >> 4;
    const int b0 = blockIdx.x * MB;
    const int n0 = blockIdx.y * MB;
    const int z  = blockIdx.z;          // 4 k-slices of 256
    float acc[4][4] = {};
    for (int kc = 0; kc < 4; ++kc) {
        const int kb = z * 256 + kc * KB;
        const float* Asrc = (kb < Hz) ? (ctx + kb) : (h_t + (kb - Hz));
        #pragma unroll
        for (int p = 0; p < 4; ++p) {
            const int row = p * 16 + ty;
            const int kk = tx * 4;
            const float4 av = *(const float4*)(Asrc + (size_t)(b0 + row) * Hz + kk);
            At[kk + 0][row] = av.x; At[kk + 1][row] = av.y;
            At[kk + 2][row] = av.z; At[kk + 3][row] = av.w;
            const float4 wv = *(const float4*)(W1 + (size_t)(n0 + row) * (2 * Hz) + kb + kk);
            Wt[kk + 0][row] = wv.x; Wt[kk + 1][row] = wv.y;
            Wt[kk + 2][row] = wv.z; Wt[kk + 3][row] = wv.w;
        }
        __syncthreads();
        #pragma unroll 16
        for (int kk = 0; kk < KB; ++kk) {
            const float4 a4 = *(const float4*)&At[kk][ty * 4];
            const float4 w4 = *(const float4*)&Wt[kk][tx * 4];
            const float ar[4] = {a4.x, a4.y, a4.z, a4.w};
            const float wr[4] = {w4.x, w4.y, w4.z, w4.w};
            #pragma unroll
            for (int i = 0; i < 4; ++i)
                #pragma unroll
                for (int j = 0; j < 4; ++j)
                    acc[i][j] = fmaf(ar[i], wr[j], acc[i][j]);
        }
        __syncthreads();
    }
    #pragma unroll
    for (int i = 0; i < 4; ++i) {
        float4 o; o.x = acc[i][0]; o.y = acc[i][1]; o.z = acc[i][2]; o.w = acc[i][3];
        *(float4*)&part[(size_t)z * ((size_t)Bz * Hz) + (size_t)(b0 + ty * 4 + i) * Hz + n0 + tx * 4] = o;
    }
}

// ---------------- reduce k-slices + tanh + W2 dot -> y[b, s] ----------------
__global__ __launch_bounds__(256) void k_out(const float* __restrict__ part,
                                             const float* __restrict__ b1,
                                             const float* __restrict__ W2,
                                             const float* __restrict__ b2,
                                             float* __restrict__ y, int s) {
    const int b = blockIdx.x;
    const int tid = threadIdx.x;
    const size_t BH = (size_t)Bz * Hz;
    float a = 0.f;
    for (int j = tid; j < Hz; j += 256) {
        const size_t o = (size_t)b * Hz + j;
        const float pre = b1[j] + part[o] + part[BH + o] + part[2 * BH + o] + part[3 * BH + o];
        a = fmaf(tanhf(pre), W2[j], a);
    }
    #pragma unroll
    for (int d = 1; d < 64; d <<= 1) a += __shfl_xor(a, d);
    __shared__ float r[4];
    if ((tid & 63) == 0) r[tid >> 6] = a;
    __syncthreads();
    if (tid == 0) y[(size_t)b * PLz + s] = r[0] + r[1] + r[2] + r[3] + b2[0];
}

extern "C" void kernel_launch(void* const* d_in, const int* in_sizes, int n_in,
                              void* d_out, int out_size, void* d_ws, size_t ws_size,
                              hipStream_t stream) {
    (void)in_sizes; (void)n_in; (void)out_size; (void)ws_size;
    const float* x     = (const float*)d_in[0];
    const float* W_ih  = (const float*)d_in[1];
    const float* W_hh  = (const float*)d_in[2];
    const float* b_l   = (const float*)d_in[3];
    const float* Wc_ih = (const float*)d_in[4];
    const float* Wc_hh = (const float*)d_in[5];
    const float* b_c   = (const float*)d_in[6];
    const float* W1    = (const float*)d_in[7];
    const float* b1    = (const float*)d_in[8];
    const float* W2    = (const float*)d_in[9];
    const float* b2    = (const float*)d_in[10];
    float* y = (float*)d_out;

    float* w = (float*)d_ws;
    const size_t BH = (size_t)Bz * Hz;
    float* h_a = w;
    float* h_b = w + BH;
    float* c   = w + 2 * BH;
    float* buf = w + 3 * BH;                       // B*TS*H
    float* Wc  = buf + (size_t)Bz * TSz * Hz;      // G*H
    float* ctx = Wc + (size_t)Gz * Hz;             // B*H
    float* part = ctx + BH;                        // 4*B*H

    k_init<<<dim3((Gz * Hz + 255) / 256), dim3(256), 0, stream>>>(Wc_ih, Wc_hh, Wc, h_a, c);

    // encoder: 128 steps, h ping-pong; ring buffer slot t&31 (final = Hs[:, 96..127])
    float* hin = h_a; float* hout = h_b;
    for (int t = 0; t < Tz; ++t) {
        k_step<<<dim3(8, 32), dim3(256), 0, stream>>>(x, t, W_ih, W_hh, b_l,
                                                      hin, hout, c, buf, t & 31);
        float* tmp = hin; hin = hout; hout = tmp;
    }
    // decoder: 32 steps
    for (int s = 0; s < PLz; ++s) {
        k_step<<<dim3(8, 32), dim3(256), 0, stream>>>(nullptr, 0, nullptr, Wc, b_c,
                                                      hin, hout, c, buf, -1);
        k_attn<<<dim3(Bz), dim3(256), 0, stream>>>(hout, buf, ctx, s & 31);
        k_mlp<<<dim3(8, 8, 4), dim3(256), 0, stream>>>(ctx, hout, W1, part);
        k_out<<<dim3(Bz), dim3(256), 0, stream>>>(part, b1, W2, b2, y, s);
        float* tmp = hin; hin = hout; hout = tmp;
    }
}

// Round 2
// 4200.204 us; speedup vs baseline: 2.3346x; 2.3346x over previous
//
#include <hip/hip_runtime.h>
#include <hip/hip_bf16.h>
#include <math.h>

// Problem sizes
#define Bz   512
#define Tz   128
#define INz  64
#define Hz   512
#define Gz   2048
#define TSz  32
#define PLz  32
#define BH   (Bz * Hz)          // 262144

typedef __attribute__((ext_vector_type(8)))  short short8;
typedef __attribute__((ext_vector_type(16))) float floatx16;

static __device__ __forceinline__ void split_bf(float w, unsigned short& hi, unsigned short& lo) {
    __hip_bfloat16 h = __float2bfloat16(w);
    hi = *reinterpret_cast<unsigned short*>(&h);
    float r = w - __bfloat162float(h);
    __hip_bfloat16 l = __float2bfloat16(r);
    lo = *reinterpret_cast<unsigned short*>(&l);
}

// ---------------- init: zero c and initial h fragments ----------------
__global__ __launch_bounds__(256) void k_init(float* __restrict__ c,
                                              unsigned short* __restrict__ hf_hi,
                                              unsigned short* __restrict__ hf_lo) {
    const int i = blockIdx.x * 256 + threadIdx.x;
    if (i < BH) { c[i] = 0.f; hf_hi[i] = 0; hf_lo[i] = 0; }
}

// ---------------- prep: encoder W fragments (gate-permuted cols, K=576=64x|512h) ----------------
// col C in [0,2048): gate = ((C>>4)&3)*512 + (C>>6)*16 + (C&15)
__global__ __launch_bounds__(256) void k_prep_wenc(const float* __restrict__ W_ih,
                                                   const float* __restrict__ W_hh,
                                                   unsigned short* __restrict__ wf_hi,
                                                   unsigned short* __restrict__ wf_lo) {
    const int idx = blockIdx.x * 256 + threadIdx.x;   // (cb*36+g)*64+lane, 64*36*64
    const int lane = idx & 63;
    const int g = (idx >> 6) % 36;
    const int cb = idx / (36 * 64);
    const int C = cb * 32 + (lane & 31);
    const int gate = ((C >> 4) & 3) * 512 + (C >> 6) * 16 + (C & 15);
    const int kh = lane >> 5;
    const size_t base = (size_t)idx * 8;
    #pragma unroll
    for (int e = 0; e < 8; ++e) {
        const int k = g * 16 + kh * 8 + e;   // [0,576)
        const float w = (k < 64) ? W_ih[(size_t)gate * 64 + k]
                                 : W_hh[(size_t)gate * 512 + (k - 64)];
        unsigned short hi, lo; split_bf(w, hi, lo);
        wf_hi[base + e] = hi; wf_lo[base + e] = lo;
    }
}

// ---------------- prep: decoder W fragments (Wc = Wc_ih + Wc_hh, K=512) ----------------
__global__ __launch_bounds__(256) void k_prep_wc(const float* __restrict__ Wc_ih,
                                                 const float* __restrict__ Wc_hh,
                                                 unsigned short* __restrict__ wf_hi,
                                                 unsigned short* __restrict__ wf_lo) {
    const int idx = blockIdx.x * 256 + threadIdx.x;   // 64*32*64
    const int lane = idx & 63;
    const int cb = idx / (32 * 64);
    const int g = (idx >> 6) % 32;
    const int C = cb * 32 + (lane & 31);
    const int gate = ((C >> 4) & 3) * 512 + (C >> 6) * 16 + (C & 15);
    const int kh = lane >> 5;
    const size_t base = (size_t)idx * 8;
    #pragma unroll
    for (int e = 0; e < 8; ++e) {
        const int k = g * 16 + kh * 8 + e;   // [0,512)
        const float w = Wc_ih[(size_t)gate * 512 + k] + Wc_hh[(size_t)gate * 512 + k];
        unsigned short hi, lo; split_bf(w, hi, lo);
        wf_hi[base + e] = hi; wf_lo[base + e] = lo;
    }
}

// ---------------- prep: W1 fragments (plain cols, K=1024) ----------------
__global__ __launch_bounds__(256) void k_prep_w1(const float* __restrict__ W1,
                                                 unsigned short* __restrict__ wf_hi,
                                                 unsigned short* __restrict__ wf_lo) {
    const int idx = blockIdx.x * 256 + threadIdx.x;   // 16*64*64
    const int lane = idx & 63;
    const int cb = idx / (64 * 64);
    const int g = (idx >> 6) % 64;
    const int n = cb * 32 + (lane & 31);
    const int kh = lane >> 5;
    const size_t base = (size_t)idx * 8;
    #pragma unroll
    for (int e = 0; e < 8; ++e) {
        const int k = g * 16 + kh * 8 + e;   // [0,1024)
        const float w = W1[(size_t)n * 1024 + k];
        unsigned short hi, lo; split_bf(w, hi, lo);
        wf_hi[base + e] = hi; wf_lo[base + e] = lo;
    }
}

// ---------------- prep: x fragments xf[t][rb][g][lane][8] ----------------
__global__ __launch_bounds__(256) void k_prep_x(const float* __restrict__ x,
                                                unsigned short* __restrict__ xf_hi,
                                                unsigned short* __restrict__ xf_lo) {
    const int idx = blockIdx.x * 256 + threadIdx.x;   // 128*16*4*64 = 524288
    const int lane = idx & 63;
    const int g = (idx >> 6) & 3;
    const int rb = (idx >> 8) & 15;
    const int t = idx >> 12;
    const int b = rb * 32 + (lane & 31);
    const int kh = lane >> 5;
    const size_t base = (size_t)idx * 8;
    #pragma unroll
    for (int e = 0; e < 8; ++e) {
        const int i = g * 16 + kh * 8 + e;   // [0,64)
        const float w = x[((size_t)b * Tz + t) * INz + i];
        unsigned short hi, lo; split_bf(w, hi, lo);
        xf_hi[base + e] = hi; xf_lo[base + e] = lo;
    }
}

// ---------------- fused LSTM step: split-bf16 MFMA GEMM + cell update ----------------
// grid (8,32): bi=row-block(64), ji=col-block(64 permuted gate-cols). 4 waves of 32x32.
__global__ __launch_bounds__(256) void k_step(
    const unsigned short* __restrict__ xf_hi, const unsigned short* __restrict__ xf_lo,
    int t, int gx, int NG,
    const unsigned short* __restrict__ wf_hi, const unsigned short* __restrict__ wf_lo,
    const unsigned short* __restrict__ hf_in_hi, const unsigned short* __restrict__ hf_in_lo,
    const float* __restrict__ bias,
    float* __restrict__ c, float* __restrict__ h_f32,
    unsigned short* __restrict__ hf_out_hi, unsigned short* __restrict__ hf_out_lo,
    float* __restrict__ buf, int slot)
{
    __shared__ float Gt[64][64];
    const int tid = threadIdx.x;
    const int lane = tid & 63, wid = tid >> 6;
    const int wr = wid >> 1, wc = wid & 1;
    const int bi = blockIdx.x, ji = blockIdx.y;
    const int rbIdx = bi * 2 + wr;       // 32-row fragment block
    const int cbIdx = ji * 2 + wc;       // 32-col fragment block

    floatx16 acc;
    #pragma unroll
    for (int i = 0; i < 16; ++i) acc[i] = 0.f;

    const unsigned short* pb_hi = wf_hi + ((size_t)cbIdx * NG) * 512 + lane * 8;
    const unsigned short* pb_lo = wf_lo + ((size_t)cbIdx * NG) * 512 + lane * 8;

    #pragma unroll 4
    for (int g = 0; g < NG; ++g) {
        const unsigned short* pa_hi;
        const unsigned short* pa_lo;
        if (g < gx) {
            const size_t off = ((((size_t)t * 16 + rbIdx) * 4 + g) * 64 + lane) * 8;
            pa_hi = xf_hi + off; pa_lo = xf_lo + off;
        } else {
            const size_t off = (((size_t)rbIdx * 32 + (g - gx)) * 64 + lane) * 8;
            pa_hi = hf_in_hi + off; pa_lo = hf_in_lo + off;
        }
        const short8 ah = *(const short8*)pa_hi;
        const short8 al = *(const short8*)pa_lo;
        const short8 bh = *(const short8*)(pb_hi + (size_t)g * 512);
        const short8 bl = *(const short8*)(pb_lo + (size_t)g * 512);
        acc = __builtin_amdgcn_mfma_f32_32x32x16_bf16(ah, bh, acc, 0, 0, 0);
        acc = __builtin_amdgcn_mfma_f32_32x32x16_bf16(ah, bl, acc, 0, 0, 0);
        acc = __builtin_amdgcn_mfma_f32_32x32x16_bf16(al, bh, acc, 0, 0, 0);
    }

    // ---- dump 32x32 frags to Gt[64][64] (conflict-free: lanes hit distinct banks) ----
    {
        const int col = wc * 32 + (lane & 31);
        const int rbase = wr * 32 + 4 * (lane >> 5);
        #pragma unroll
        for (int r = 0; r < 16; ++r) {
            const int row = rbase + (r & 3) + 8 * (r >> 2);
            Gt[row][col] = acc[r];
        }
    }
    __syncthreads();

    // ---- cell update: 64 b x 16 jj per block; Gt col = q*16+jj -> gate q*512 + ji*16 + jj ----
    #pragma unroll
    for (int rr = 0; rr < 4; ++rr) {
        const int idx = rr * 256 + tid;
        const int bl = idx >> 4, jj = idx & 15;
        const int b = bi * 64 + bl;
        const int j = ji * 16 + jj;
        const float gi = Gt[bl][jj]       + bias[j];
        const float gf = Gt[bl][16 + jj]  + bias[512 + j];
        const float gg = Gt[bl][32 + jj]  + bias[1024 + j];
        const float go = Gt[bl][48 + jj]  + bias[1536 + j];
        const float si = 1.f / (1.f + __expf(-gi));
        const float sf = 1.f / (1.f + __expf(-gf));
        const float so = 1.f / (1.f + __expf(-go));
        const size_t o = (size_t)b * Hz + j;
        const float cn = sf * c[o] + si * tanhf(gg);
        const float hn = so * tanhf(cn);
        c[o] = cn;
        h_f32[o] = hn;
        // fragment-major h for next step's GEMM
        unsigned short hi, lo; split_bf(hn, hi, lo);
        const int rb = b >> 5, gran = j >> 4;
        const int fl = ((j >> 3) & 1) * 32 + (b & 31);
        const size_t fo = (((size_t)rb * 32 + gran) * 64 + fl) * 8 + (j & 7);
        hf_out_hi[fo] = hi; hf_out_lo[fo] = lo;
        if (slot >= 0) buf[((size_t)b * TSz + slot) * Hz + j] = hn;
    }
}

// ---------------- decoder attention over ring buffer + append ----------------
__global__ __launch_bounds__(256) void k_attn(const float* __restrict__ h_t,
                                              float* __restrict__ buf,
                                              unsigned short* __restrict__ ctxf_hi,
                                              unsigned short* __restrict__ ctxf_lo,
                                              int base) {
    const int b = blockIdx.x;
    const int tid = threadIdx.x;
    __shared__ float sh[Hz];
    __shared__ float sa[TSz];
    for (int i = tid; i < Hz; i += 256) sh[i] = h_t[(size_t)b * Hz + i];
    __syncthreads();
    {   // 32 dots of length 512, 8 lanes each
        const int s = tid >> 3, l8 = tid & 7;
        const float* br = buf + ((size_t)b * TSz + ((base + s) & 31)) * Hz;
        float p = 0.f;
        for (int j = l8; j < Hz; j += 8) p = fmaf(sh[j], br[j], p);
        p += __shfl_xor(p, 1); p += __shfl_xor(p, 2); p += __shfl_xor(p, 4);
        if (l8 == 0) sa[s] = p;
    }
    __syncthreads();
    if (tid < TSz) {
        const float v = sa[tid];
        float m = v;
        #pragma unroll
        for (int d = 1; d < 32; d <<= 1) m = fmaxf(m, __shfl_xor(m, d));
        const float e = __expf(v - m);
        float ssum = e;
        #pragma unroll
        for (int d = 1; d < 32; d <<= 1) ssum += __shfl_xor(ssum, d);
        sa[tid] = e / ssum;
    }
    __syncthreads();
    for (int j = tid; j < Hz; j += 256) {   // ctx -> fragment-major bf16 hi/lo
        float a = 0.f;
        #pragma unroll
        for (int s2 = 0; s2 < TSz; ++s2)
            a = fmaf(sa[s2], buf[((size_t)b * TSz + ((base + s2) & 31)) * Hz + j], a);
        unsigned short hi, lo; split_bf(a, hi, lo);
        const int rb = b >> 5, gran = j >> 4;
        const int fl = ((j >> 3) & 1) * 32 + (b & 31);
        const size_t fo = (((size_t)rb * 32 + gran) * 64 + fl) * 8 + (j & 7);
        ctxf_hi[fo] = hi; ctxf_lo[fo] = lo;
    }
    __syncthreads();
    for (int i = tid; i < Hz; i += 256) buf[((size_t)b * TSz + base) * Hz + i] = sh[i];
}

// ---------------- MLP partial GEMM via MFMA: part[z] over K-quarter z ----------------
__global__ __launch_bounds__(256) void k_mlp(
    const unsigned short* __restrict__ ctxf_hi, const unsigned short* __restrict__ ctxf_lo,
    const unsigned short* __restrict__ hf_hi,   const unsigned short* __restrict__ hf_lo,
    const unsigned short* __restrict__ w1f_hi,  const unsigned short* __restrict__ w1f_lo,
    float* __restrict__ part)
{
    const int tid = threadIdx.x;
    const int lane = tid & 63, wid = tid >> 6;
    const int wr = wid >> 1, wc = wid & 1;
    const int bi = blockIdx.x, ni = blockIdx.y, z = blockIdx.z;
    const int rbIdx = bi * 2 + wr, cbIdx = ni * 2 + wc;

    floatx16 acc;
    #pragma unroll
    for (int i = 0; i < 16; ++i) acc[i] = 0.f;

    #pragma unroll 4
    for (int g2 = 0; g2 < 16; ++g2) {
        const int g = z * 16 + g2;   // [0,64)
        const unsigned short* pa_hi;
        const unsigned short* pa_lo;
        if (g < 32) {
            const size_t off = (((size_t)rbIdx * 32 + g) * 64 + lane) * 8;
            pa_hi = ctxf_hi + off; pa_lo = ctxf_lo + off;
        } else {
            const size_t off = (((size_t)rbIdx * 32 + (g - 32)) * 64 + lane) * 8;
            pa_hi = hf_hi + off; pa_lo = hf_lo + off;
        }
        const size_t boff = (((size_t)cbIdx * 64 + g) * 64 + lane) * 8;
        const short8 ah = *(const short8*)pa_hi;
        const short8 al = *(const short8*)pa_lo;
        const short8 bh = *(const short8*)(w1f_hi + boff);
        const short8 bl = *(const short8*)(w1f_lo + boff);
        acc = __builtin_amdgcn_mfma_f32_32x32x16_bf16(ah, bh, acc, 0, 0, 0);
        acc = __builtin_amdgcn_mfma_f32_32x32x16_bf16(ah, bl, acc, 0, 0, 0);
        acc = __builtin_amdgcn_mfma_f32_32x32x16_bf16(al, bh, acc, 0, 0, 0);
    }

    const int col = ni * 64 + wc * 32 + (lane & 31);
    const int rbase = bi * 64 + wr * 32 + 4 * (lane >> 5);
    #pragma unroll
    for (int r = 0; r < 16; ++r) {
        const int row = rbase + (r & 3) + 8 * (r >> 2);
        part[(size_t)z * BH + (size_t)row * Hz + col] = acc[r];
    }
}

// ---------------- reduce k-slices + tanh + W2 dot -> y[b, s] ----------------
__global__ __launch_bounds__(256) void k_out(const float* __restrict__ part,
                                             const float* __restrict__ b1,
                                             const float* __restrict__ W2,
                                             const float* __restrict__ b2,
                                             float* __restrict__ y, int s) {
    const int b = blockIdx.x;
    const int tid = threadIdx.x;
    float a = 0.f;
    for (int j = tid; j < Hz; j += 256) {
        const size_t o = (size_t)b * Hz + j;
        const float pre = b1[j] + part[o] + part[BH + o] + part[2 * (size_t)BH + o] + part[3 * (size_t)BH + o];
        a = fmaf(tanhf(pre), W2[j], a);
    }
    #pragma unroll
    for (int d = 1; d < 64; d <<= 1) a += __shfl_xor(a, d);
    __shared__ float r[4];
    if ((tid & 63) == 0) r[tid >> 6] = a;
    __syncthreads();
    if (tid == 0) y[(size_t)b * PLz + s] = r[0] + r[1] + r[2] + r[3] + b2[0];
}

extern "C" void kernel_launch(void* const* d_in, const int* in_sizes, int n_in,
                              void* d_out, int out_size, void* d_ws, size_t ws_size,
                              hipStream_t stream) {
    (void)in_sizes; (void)n_in; (void)out_size; (void)ws_size;
    const float* x     = (const float*)d_in[0];
    const float* W_ih  = (const float*)d_in[1];
    const float* W_hh  = (const float*)d_in[2];
    const float* b_l   = (const float*)d_in[3];
    const float* Wc_ih = (const float*)d_in[4];
    const float* Wc_hh = (const float*)d_in[5];
    const float* b_c   = (const float*)d_in[6];
    const float* W1    = (const float*)d_in[7];
    const float* b1    = (const float*)d_in[8];
    const float* W2    = (const float*)d_in[9];
    const float* b2    = (const float*)d_in[10];
    float* y = (float*)d_out;

    float* w = (float*)d_ws;
    float* c     = w;                 // BH
    float* h_f32 = w + BH;            // BH
    float* buf   = w + 2 * (size_t)BH;        // 32*BH
    float* part  = w + 34 * (size_t)BH;       // 4*BH
    unsigned short* us = (unsigned short*)(w + 38 * (size_t)BH);
    unsigned short* hfa_hi = us;  us += BH;
    unsigned short* hfa_lo = us;  us += BH;
    unsigned short* hfb_hi = us;  us += BH;
    unsigned short* hfb_lo = us;  us += BH;
    unsigned short* ctxf_hi = us; us += BH;
    unsigned short* ctxf_lo = us; us += BH;
    unsigned short* xf_hi = us;   us += 4194304;   // 128*16*4*64*8
    unsigned short* xf_lo = us;   us += 4194304;
    unsigned short* wf_hi = us;   us += 1179648;   // 64*36*64*8
    unsigned short* wf_lo = us;   us += 1179648;
    unsigned short* wcf_hi = us;  us += 1048576;   // 64*32*64*8
    unsigned short* wcf_lo = us;  us += 1048576;
    unsigned short* w1f_hi = us;  us += 524288;    // 16*64*64*8
    unsigned short* w1f_lo = us;  us += 524288;

    k_init     <<<1024, 256, 0, stream>>>(c, hfa_hi, hfa_lo);
    k_prep_wenc<<<576,  256, 0, stream>>>(W_ih, W_hh, wf_hi, wf_lo);
    k_prep_wc  <<<512,  256, 0, stream>>>(Wc_ih, Wc_hh, wcf_hi, wcf_lo);
    k_prep_w1  <<<256,  256, 0, stream>>>(W1, w1f_hi, w1f_lo);
    k_prep_x   <<<2048, 256, 0, stream>>>(x, xf_hi, xf_lo);

    unsigned short *in_hi = hfa_hi, *in_lo = hfa_lo, *out_hi = hfb_hi, *out_lo = hfb_lo;

    // encoder: 128 steps (K = 64 x-part + 512 h-part)
    for (int t = 0; t < Tz; ++t) {
        k_step<<<dim3(8, 32), 256, 0, stream>>>(xf_hi, xf_lo, t, 4, 36, wf_hi, wf_lo,
                                                in_hi, in_lo, b_l, c, h_f32,
                                                out_hi, out_lo, buf, t & 31);
        unsigned short* t1 = in_hi; in_hi = out_hi; out_hi = t1;
        unsigned short* t2 = in_lo; in_lo = out_lo; out_lo = t2;
    }
    // decoder: 32 steps
    for (int s = 0; s < PLz; ++s) {
        k_step<<<dim3(8, 32), 256, 0, stream>>>(nullptr, nullptr, 0, 0, 32, wcf_hi, wcf_lo,
                                                in_hi, in_lo, b_c, c, h_f32,
                                                out_hi, out_lo, buf, -1);
        k_attn<<<dim3(Bz), 256, 0, stream>>>(h_f32, buf, ctxf_hi, ctxf_lo, s & 31);
        k_mlp <<<dim3(8, 8, 4), 256, 0, stream>>>(ctxf_hi, ctxf_lo, out_hi, out_lo,
                                                  w1f_hi, w1f_lo, part);
        k_out <<<dim3(Bz), 256, 0, stream>>>(part, b1, W2, b2, y, s);
        unsigned short* t1 = in_hi; in_hi = out_hi; out_hi = t1;
        unsigned short* t2 = in_lo; in_lo = out_lo; out_lo = t2;
    }
}

// Round 4
// 4114.553 us; speedup vs baseline: 2.3832x; 1.0208x over previous
//
#include <hip/hip_runtime.h>
#include <hip/hip_bf16.h>
#include <math.h>

// Problem sizes
#define Bz   512
#define Tz   128
#define INz  64
#define Hz   512
#define Gz   2048
#define TSz  32
#define PLz  32
#define BH   (Bz * Hz)          // 262144

typedef __attribute__((ext_vector_type(8)))  short short8;
typedef __attribute__((ext_vector_type(16))) float floatx16;

static __device__ __forceinline__ void split_bf(float w, unsigned short& hi, unsigned short& lo) {
    __hip_bfloat16 h = __float2bfloat16(w);
    hi = *reinterpret_cast<unsigned short*>(&h);
    float r = w - __bfloat162float(h);
    __hip_bfloat16 l = __float2bfloat16(r);
    lo = *reinterpret_cast<unsigned short*>(&l);
}

// ---------------- init: zero c and initial h fragments ----------------
__global__ __launch_bounds__(256) void k_init(float* __restrict__ c,
                                              unsigned short* __restrict__ hf_hi,
                                              unsigned short* __restrict__ hf_lo) {
    const int i = blockIdx.x * 256 + threadIdx.x;
    if (i < BH) { c[i] = 0.f; hf_hi[i] = 0; hf_lo[i] = 0; }
}

// ---------------- prep: encoder W fragments (gate-permuted cols, K=576=64x|512h) ----------------
__global__ __launch_bounds__(256) void k_prep_wenc(const float* __restrict__ W_ih,
                                                   const float* __restrict__ W_hh,
                                                   unsigned short* __restrict__ wf_hi,
                                                   unsigned short* __restrict__ wf_lo) {
    const int idx = blockIdx.x * 256 + threadIdx.x;   // (cb*36+g)*64+lane
    const int lane = idx & 63;
    const int g = (idx >> 6) % 36;
    const int cb = idx / (36 * 64);
    const int C = cb * 32 + (lane & 31);
    const int gate = ((C >> 4) & 3) * 512 + (C >> 6) * 16 + (C & 15);
    const int kh = lane >> 5;
    const size_t base = (size_t)idx * 8;
    #pragma unroll
    for (int e = 0; e < 8; ++e) {
        const int k = g * 16 + kh * 8 + e;   // [0,576)
        const float w = (k < 64) ? W_ih[(size_t)gate * 64 + k]
                                 : W_hh[(size_t)gate * 512 + (k - 64)];
        unsigned short hi, lo; split_bf(w, hi, lo);
        wf_hi[base + e] = hi; wf_lo[base + e] = lo;
    }
}

// ---------------- prep: decoder W fragments (Wc = Wc_ih + Wc_hh, K=512) ----------------
__global__ __launch_bounds__(256) void k_prep_wc(const float* __restrict__ Wc_ih,
                                                 const float* __restrict__ Wc_hh,
                                                 unsigned short* __restrict__ wf_hi,
                                                 unsigned short* __restrict__ wf_lo) {
    const int idx = blockIdx.x * 256 + threadIdx.x;
    const int lane = idx & 63;
    const int cb = idx / (32 * 64);
    const int g = (idx >> 6) % 32;
    const int C = cb * 32 + (lane & 31);
    const int gate = ((C >> 4) & 3) * 512 + (C >> 6) * 16 + (C & 15);
    const int kh = lane >> 5;
    const size_t base = (size_t)idx * 8;
    #pragma unroll
    for (int e = 0; e < 8; ++e) {
        const int k = g * 16 + kh * 8 + e;
        const float w = Wc_ih[(size_t)gate * 512 + k] + Wc_hh[(size_t)gate * 512 + k];
        unsigned short hi, lo; split_bf(w, hi, lo);
        wf_hi[base + e] = hi; wf_lo[base + e] = lo;
    }
}

// ---------------- prep: W1 fragments (plain cols, K=1024) ----------------
__global__ __launch_bounds__(256) void k_prep_w1(const float* __restrict__ W1,
                                                 unsigned short* __restrict__ wf_hi,
                                                 unsigned short* __restrict__ wf_lo) {
    const int idx = blockIdx.x * 256 + threadIdx.x;
    const int lane = idx & 63;
    const int cb = idx / (64 * 64);
    const int g = (idx >> 6) % 64;
    const int n = cb * 32 + (lane & 31);
    const int kh = lane >> 5;
    const size_t base = (size_t)idx * 8;
    #pragma unroll
    for (int e = 0; e < 8; ++e) {
        const int k = g * 16 + kh * 8 + e;
        const float w = W1[(size_t)n * 1024 + k];
        unsigned short hi, lo; split_bf(w, hi, lo);
        wf_hi[base + e] = hi; wf_lo[base + e] = lo;
    }
}

// ---------------- prep: x fragments xf[t][rb][g][lane][8] ----------------
__global__ __launch_bounds__(256) void k_prep_x(const float* __restrict__ x,
                                                unsigned short* __restrict__ xf_hi,
                                                unsigned short* __restrict__ xf_lo) {
    const int idx = blockIdx.x * 256 + threadIdx.x;
    const int lane = idx & 63;
    const int g = (idx >> 6) & 3;
    const int rb = (idx >> 8) & 15;
    const int t = idx >> 12;
    const int b = rb * 32 + (lane & 31);
    const int kh = lane >> 5;
    const size_t base = (size_t)idx * 8;
    #pragma unroll
    for (int e = 0; e < 8; ++e) {
        const int i = g * 16 + kh * 8 + e;
        const float w = x[((size_t)b * Tz + t) * INz + i];
        unsigned short hi, lo; split_bf(w, hi, lo);
        xf_hi[base + e] = hi; xf_lo[base + e] = lo;
    }
}

// ---------------- fused LSTM step: split-bf16 MFMA GEMM + cell update ----------------
// grid (32, 8): x = ji (col-block; weight-sharing blocks co-locate per XCD), y = bi.
// Compile-time NG/GX -> full unroll; consume-then-refill depth-PF register pipeline.
#define PF 4
template<int NG, int GX>
__global__ __launch_bounds__(256) void k_step(
    const unsigned short* __restrict__ xf_hi, const unsigned short* __restrict__ xf_lo,
    int t,
    const unsigned short* __restrict__ wf_hi, const unsigned short* __restrict__ wf_lo,
    const unsigned short* __restrict__ hf_in_hi, const unsigned short* __restrict__ hf_in_lo,
    const float* __restrict__ bias,
    float* __restrict__ c, float* __restrict__ h_f32,
    unsigned short* __restrict__ hf_out_hi, unsigned short* __restrict__ hf_out_lo,
    float* __restrict__ buf, int slot)
{
    __shared__ float Gt[64][64];
    const int tid = threadIdx.x;
    const int lane = tid & 63, wid = tid >> 6;
    const int wr = wid >> 1, wc = wid & 1;
    const int ji = blockIdx.x, bi = blockIdx.y;
    const int rbIdx = bi * 2 + wr;
    const int cbIdx = ji * 2 + wc;

    floatx16 acc0, acc1, acc2;
    #pragma unroll
    for (int i = 0; i < 16; ++i) { acc0[i] = 0.f; acc1[i] = 0.f; acc2[i] = 0.f; }

    const unsigned short* pb_hi = wf_hi + ((size_t)cbIdx * NG) * 512 + lane * 8;
    const unsigned short* pb_lo = wf_lo + ((size_t)cbIdx * NG) * 512 + lane * 8;

    short8 ah[PF], al[PF], bh[PF], bl[PF];

    #pragma unroll
    for (int g = 0; g < NG + PF; ++g) {
        // ---- consume granule g-PF (slot freed before refill below) ----
        if (g >= PF) {
            const int s = (g - PF) & (PF - 1);
            acc0 = __builtin_amdgcn_mfma_f32_32x32x16_bf16(ah[s], bh[s], acc0, 0, 0, 0);
            acc1 = __builtin_amdgcn_mfma_f32_32x32x16_bf16(ah[s], bl[s], acc1, 0, 0, 0);
            acc2 = __builtin_amdgcn_mfma_f32_32x32x16_bf16(al[s], bh[s], acc2, 0, 0, 0);
        }
        // ---- refill slot with granule g ----
        if (g < NG) {
            const int s = g & (PF - 1);
            const unsigned short* pa_hi;
            const unsigned short* pa_lo;
            if (g < GX) {
                const size_t off = ((((size_t)t * 16 + rbIdx) * 4 + g) * 64 + lane) * 8;
                pa_hi = xf_hi + off; pa_lo = xf_lo + off;
            } else {
                const size_t off = (((size_t)rbIdx * 32 + (g - GX)) * 64 + lane) * 8;
                pa_hi = hf_in_hi + off; pa_lo = hf_in_lo + off;
            }
            ah[s] = *(const short8*)pa_hi;
            al[s] = *(const short8*)pa_lo;
            bh[s] = *(const short8*)(pb_hi + (size_t)g * 512);
            bl[s] = *(const short8*)(pb_lo + (size_t)g * 512);
        }
    }
    #pragma unroll
    for (int i = 0; i < 16; ++i) acc0[i] += acc1[i] + acc2[i];

    // ---- dump 32x32 frags to Gt[64][64] ----
    {
        const int col = wc * 32 + (lane & 31);
        const int rbase = wr * 32 + 4 * (lane >> 5);
        #pragma unroll
        for (int r = 0; r < 16; ++r) {
            const int row = rbase + (r & 3) + 8 * (r >> 2);
            Gt[row][col] = acc0[r];
        }
    }
    __syncthreads();

    // ---- cell update: 64 b x 16 jj per block ----
    #pragma unroll
    for (int rr = 0; rr < 4; ++rr) {
        const int idx = rr * 256 + tid;
        const int bl2 = idx >> 4, jj = idx & 15;
        const int b = bi * 64 + bl2;
        const int j = ji * 16 + jj;
        const float gi = Gt[bl2][jj]       + bias[j];
        const float gf = Gt[bl2][16 + jj]  + bias[512 + j];
        const float gg = Gt[bl2][32 + jj]  + bias[1024 + j];
        const float go = Gt[bl2][48 + jj]  + bias[1536 + j];
        const float si = 1.f / (1.f + __expf(-gi));
        const float sf = 1.f / (1.f + __expf(-gf));
        const float so = 1.f / (1.f + __expf(-go));
        const size_t o = (size_t)b * Hz + j;
        const float cn = sf * c[o] + si * tanhf(gg);
        const float hn = so * tanhf(cn);
        c[o] = cn;
        h_f32[o] = hn;
        unsigned short hi, lo; split_bf(hn, hi, lo);
        const int rb = b >> 5, gran = j >> 4;
        const int fl = ((j >> 3) & 1) * 32 + (b & 31);
        const size_t fo = (((size_t)rb * 32 + gran) * 64 + fl) * 8 + (j & 7);
        hf_out_hi[fo] = hi; hf_out_lo[fo] = lo;
        if (slot >= 0) buf[((size_t)b * TSz + slot) * Hz + j] = hn;
    }
}

// ---------------- decoder attention over ring buffer + append ----------------
__global__ __launch_bounds__(256) void k_attn(const float* __restrict__ h_t,
                                              float* __restrict__ buf,
                                              unsigned short* __restrict__ ctxf_hi,
                                              unsigned short* __restrict__ ctxf_lo,
                                              int base) {
    const int b = blockIdx.x;
    const int tid = threadIdx.x;
    __shared__ float sh[Hz];
    __shared__ float sa[TSz];
    for (int i = tid; i < Hz; i += 256) sh[i] = h_t[(size_t)b * Hz + i];
    __syncthreads();
    {
        const int s = tid >> 3, l8 = tid & 7;
        const float* br = buf + ((size_t)b * TSz + ((base + s) & 31)) * Hz;
        float p = 0.f;
        for (int j = l8; j < Hz; j += 8) p = fmaf(sh[j], br[j], p);
        p += __shfl_xor(p, 1); p += __shfl_xor(p, 2); p += __shfl_xor(p, 4);
        if (l8 == 0) sa[s] = p;
    }
    __syncthreads();
    if (tid < TSz) {
        const float v = sa[tid];
        float m = v;
        #pragma unroll
        for (int d = 1; d < 32; d <<= 1) m = fmaxf(m, __shfl_xor(m, d));
        const float e = __expf(v - m);
        float ssum = e;
        #pragma unroll
        for (int d = 1; d < 32; d <<= 1) ssum += __shfl_xor(ssum, d);
        sa[tid] = e / ssum;
    }
    __syncthreads();
    for (int j = tid; j < Hz; j += 256) {
        float a = 0.f;
        #pragma unroll
        for (int s2 = 0; s2 < TSz; ++s2)
            a = fmaf(sa[s2], buf[((size_t)b * TSz + ((base + s2) & 31)) * Hz + j], a);
        unsigned short hi, lo; split_bf(a, hi, lo);
        const int rb = b >> 5, gran = j >> 4;
        const int fl = ((j >> 3) & 1) * 32 + (b & 31);
        const size_t fo = (((size_t)rb * 32 + gran) * 64 + fl) * 8 + (j & 7);
        ctxf_hi[fo] = hi; ctxf_lo[fo] = lo;
    }
    __syncthreads();
    for (int i = tid; i < Hz; i += 256) buf[((size_t)b * TSz + base) * Hz + i] = sh[i];
}

// ---------------- MLP partial GEMM via MFMA: part[z] over K-quarter z ----------------
// grid (8(ni), 8(bi), 4(z)) -> same-ni blocks co-locate per XCD (share W1 cols)
__global__ __launch_bounds__(256) void k_mlp(
    const unsigned short* __restrict__ ctxf_hi, const unsigned short* __restrict__ ctxf_lo,
    const unsigned short* __restrict__ hf_hi,   const unsigned short* __restrict__ hf_lo,
    const unsigned short* __restrict__ w1f_hi,  const unsigned short* __restrict__ w1f_lo,
    float* __restrict__ part)
{
    const int tid = threadIdx.x;
    const int lane = tid & 63, wid = tid >> 6;
    const int wr = wid >> 1, wc = wid & 1;
    const int ni = blockIdx.x, bi = blockIdx.y, z = blockIdx.z;
    const int rbIdx = bi * 2 + wr, cbIdx = ni * 2 + wc;

    floatx16 acc0, acc1, acc2;
    #pragma unroll
    for (int i = 0; i < 16; ++i) { acc0[i] = 0.f; acc1[i] = 0.f; acc2[i] = 0.f; }

    short8 ah[PF], al[PF], bh[PF], bl[PF];

    #pragma unroll
    for (int gg = 0; gg < 16 + PF; ++gg) {
        // ---- consume granule gg-PF ----
        if (gg >= PF) {
            const int s = (gg - PF) & (PF - 1);
            acc0 = __builtin_amdgcn_mfma_f32_32x32x16_bf16(ah[s], bh[s], acc0, 0, 0, 0);
            acc1 = __builtin_amdgcn_mfma_f32_32x32x16_bf16(ah[s], bl[s], acc1, 0, 0, 0);
            acc2 = __builtin_amdgcn_mfma_f32_32x32x16_bf16(al[s], bh[s], acc2, 0, 0, 0);
        }
        // ---- refill with granule gg ----
        if (gg < 16) {
            const int s = gg & (PF - 1);
            const int g = z * 16 + gg;   // [0,64)
            const unsigned short* pa_hi;
            const unsigned short* pa_lo;
            if (g < 32) {
                const size_t off = (((size_t)rbIdx * 32 + g) * 64 + lane) * 8;
                pa_hi = ctxf_hi + off; pa_lo = ctxf_lo + off;
            } else {
                const size_t off = (((size_t)rbIdx * 32 + (g - 32)) * 64 + lane) * 8;
                pa_hi = hf_hi + off; pa_lo = hf_lo + off;
            }
            const size_t boff = (((size_t)cbIdx * 64 + g) * 64 + lane) * 8;
            ah[s] = *(const short8*)pa_hi;
            al[s] = *(const short8*)pa_lo;
            bh[s] = *(const short8*)(w1f_hi + boff);
            bl[s] = *(const short8*)(w1f_lo + boff);
        }
    }
    #pragma unroll
    for (int i = 0; i < 16; ++i) acc0[i] += acc1[i] + acc2[i];

    const int col = ni * 64 + wc * 32 + (lane & 31);
    const int rbase = bi * 64 + wr * 32 + 4 * (lane >> 5);
    #pragma unroll
    for (int r = 0; r < 16; ++r) {
        const int row = rbase + (r & 3) + 8 * (r >> 2);
        part[(size_t)z * BH + (size_t)row * Hz + col] = acc0[r];
    }
}

// ---------------- reduce k-slices + tanh + W2 dot -> y[b, s] ----------------
__global__ __launch_bounds__(256) void k_out(const float* __restrict__ part,
                                             const float* __restrict__ b1,
                                             const float* __restrict__ W2,
                                             const float* __restrict__ b2,
                                             float* __restrict__ y, int s) {
    const int b = blockIdx.x;
    const int tid = threadIdx.x;
    float a = 0.f;
    for (int j = tid; j < Hz; j += 256) {
        const size_t o = (size_t)b * Hz + j;
        const float pre = b1[j] + part[o] + part[BH + o] + part[2 * (size_t)BH + o] + part[3 * (size_t)BH + o];
        a = fmaf(tanhf(pre), W2[j], a);
    }
    #pragma unroll
    for (int d = 1; d < 64; d <<= 1) a += __shfl_xor(a, d);
    __shared__ float r[4];
    if ((tid & 63) == 0) r[tid >> 6] = a;
    __syncthreads();
    if (tid == 0) y[(size_t)b * PLz + s] = r[0] + r[1] + r[2] + r[3] + b2[0];
}

extern "C" void kernel_launch(void* const* d_in, const int* in_sizes, int n_in,
                              void* d_out, int out_size, void* d_ws, size_t ws_size,
                              hipStream_t stream) {
    (void)in_sizes; (void)n_in; (void)out_size; (void)ws_size;
    const float* x     = (const float*)d_in[0];
    const float* W_ih  = (const float*)d_in[1];
    const float* W_hh  = (const float*)d_in[2];
    const float* b_l   = (const float*)d_in[3];
    const float* Wc_ih = (const float*)d_in[4];
    const float* Wc_hh = (const float*)d_in[5];
    const float* b_c   = (const float*)d_in[6];
    const float* W1    = (const float*)d_in[7];
    const float* b1    = (const float*)d_in[8];
    const float* W2    = (const float*)d_in[9];
    const float* b2    = (const float*)d_in[10];
    float* y = (float*)d_out;

    float* w = (float*)d_ws;
    float* c     = w;                 // BH
    float* h_f32 = w + BH;            // BH
    float* buf   = w + 2 * (size_t)BH;        // 32*BH
    float* part  = w + 34 * (size_t)BH;       // 4*BH
    unsigned short* us = (unsigned short*)(w + 38 * (size_t)BH);
    unsigned short* hfa_hi = us;  us += BH;
    unsigned short* hfa_lo = us;  us += BH;
    unsigned short* hfb_hi = us;  us += BH;
    unsigned short* hfb_lo = us;  us += BH;
    unsigned short* ctxf_hi = us; us += BH;
    unsigned short* ctxf_lo = us; us += BH;
    unsigned short* xf_hi = us;   us += 4194304;   // 128*16*4*64*8
    unsigned short* xf_lo = us;   us += 4194304;
    unsigned short* wf_hi = us;   us += 1179648;   // 64*36*64*8
    unsigned short* wf_lo = us;   us += 1179648;
    unsigned short* wcf_hi = us;  us += 1048576;   // 64*32*64*8
    unsigned short* wcf_lo = us;  us += 1048576;
    unsigned short* w1f_hi = us;  us += 524288;    // 16*64*64*8
    unsigned short* w1f_lo = us;  us += 524288;

    k_init     <<<1024, 256, 0, stream>>>(c, hfa_hi, hfa_lo);
    k_prep_wenc<<<576,  256, 0, stream>>>(W_ih, W_hh, wf_hi, wf_lo);
    k_prep_wc  <<<512,  256, 0, stream>>>(Wc_ih, Wc_hh, wcf_hi, wcf_lo);
    k_prep_w1  <<<256,  256, 0, stream>>>(W1, w1f_hi, w1f_lo);
    k_prep_x   <<<2048, 256, 0, stream>>>(x, xf_hi, xf_lo);

    unsigned short *in_hi = hfa_hi, *in_lo = hfa_lo, *out_hi = hfb_hi, *out_lo = hfb_lo;

    // encoder: 128 steps (K = 64 x-part + 512 h-part)
    for (int t = 0; t < Tz; ++t) {
        k_step<36, 4><<<dim3(32, 8), 256, 0, stream>>>(xf_hi, xf_lo, t, wf_hi, wf_lo,
                                                       in_hi, in_lo, b_l, c, h_f32,
                                                       out_hi, out_lo, buf, t & 31);
        unsigned short* t1 = in_hi; in_hi = out_hi; out_hi = t1;
        unsigned short* t2 = in_lo; in_lo = out_lo; out_lo = t2;
    }
    // decoder: 32 steps
    for (int s = 0; s < PLz; ++s) {
        k_step<32, 0><<<dim3(32, 8), 256, 0, stream>>>(nullptr, nullptr, 0, wcf_hi, wcf_lo,
                                                       in_hi, in_lo, b_c, c, h_f32,
                                                       out_hi, out_lo, buf, -1);
        k_attn<<<dim3(Bz), 256, 0, stream>>>(h_f32, buf, ctxf_hi, ctxf_lo, s & 31);
        k_mlp <<<dim3(8, 8, 4), 256, 0, stream>>>(ctxf_hi, ctxf_lo, out_hi, out_lo,
                                                  w1f_hi, w1f_lo, part);
        k_out <<<dim3(Bz), 256, 0, stream>>>(part, b1, W2, b2, y, s);
        unsigned short* t1 = in_hi; in_hi = out_hi; out_hi = t1;
        unsigned short* t2 = in_lo; in_lo = out_lo; out_lo = t2;
    }
}